// Round 11
// baseline (145.599 us; speedup 1.0000x reference)
//
#include <hip/hip_runtime.h>
#include <math.h>

#define BATCH 2048
#define SEQ 512
#define DIM 128

// DPP rotate-within-16 add: after ror 1,2,4,8 every lane holds its 16-group sum.
template<int CTRL>
__device__ __forceinline__ float dpp_add(float x) {
    int y = __builtin_amdgcn_update_dpp(0, __float_as_int(x), CTRL, 0xf, 0xf, true);
    return x + __int_as_float(y);
}

// Single fused kernel. Per-block prep (qk/qp/c0 -> LDS) costs 64 FMA/thread
// against L2-hot Wk and overlaps the 6 in-flight x prefetch loads; saves the
// serialized 1-block prep dispatch + graph launch gap.
__global__ __launch_bounds__(256, 8) void ap_fused(
    const float* __restrict__ x, const float* __restrict__ pos,
    const int* __restrict__ mask, const float* __restrict__ query,
    const float* __restrict__ Wk, const float* __restrict__ bk,
    const float* __restrict__ Wv, const float* __restrict__ bv,
    const float* __restrict__ Wp, const float* __restrict__ bp,
    float* __restrict__ out)
{
    __shared__ alignas(16) float sqk[136];  // [0..127] qk, [128..131] qp, [132] c0
    __shared__ float ppart[128];
    __shared__ float pq[128][4];
    __shared__ float pc[128];
    __shared__ float spos[520];             // padded: idx = s + (s>>7)
    __shared__ float sacc[8][DIM];
    __shared__ float sm[8], sl[8];
    __shared__ alignas(16) float t[DIM];

    const int b   = blockIdx.x;
    const int tid = threadIdx.x;
    const int l   = tid & 63;
    const int w   = tid >> 6;         // wave 0..3, owns rows [128w, 128w+128)
    const int h   = (tid >> 5) & 1;   // half: even(0)/odd(1) rows of the wave
    const int c   = tid & 31;         // column group (4 floats)
    const int st  = tid >> 5;         // merge state 0..7

    // ---- issue first 6 x-loads immediately (hide prep + spos under them) ----
    const float4* xw = (const float4*)(x + (size_t)b * SEQ * DIM) + w * 4096;
    float4 v0 = xw[0 * 64 + l];
    float4 v1 = xw[1 * 64 + l];
    float4 v2 = xw[2 * 64 + l];
    float4 v3 = xw[3 * 64 + l];
    float4 v4 = xw[4 * 64 + l];
    float4 v5 = xw[5 * 64 + l];

    // ---- fused prep: qk = S2*Wk^T q ; qp = S2*Wp^T q ; c0 = S2*q.(bk+bp) ----
    {
        const float S2 = 0.08838834764831845f * 1.4426950408889634f;  // 128^-0.5 * log2e
        const int d = tid & 127, hk = tid >> 7;   // 2 threads per output d, k-split
        float acc = 0.f;
        const int k0 = hk * 64;
        #pragma unroll 16
        for (int k = 0; k < 64; ++k) acc += query[k0 + k] * Wk[(k0 + k) * 128 + d];
        if (hk) ppart[d] = acc;
        if (tid < 128) {
            float q = query[tid];
            float4 wp = ((const float4*)Wp)[tid];
            pq[tid][0] = q * wp.x; pq[tid][1] = q * wp.y;
            pq[tid][2] = q * wp.z; pq[tid][3] = q * wp.w;
            pc[tid] = q * (bk[tid] + bp[tid]);
        }
        __syncthreads();
        if (!hk) {
            sqk[d] = (acc + ppart[d]) * S2;
        } else if (d < 4) {
            float s = 0.f;
            #pragma unroll
            for (int k = 0; k < 128; ++k) s += pq[k][d];
            sqk[128 + d] = s * S2;
        } else if (d == 4) {
            float s = 0.f;
            #pragma unroll
            for (int k = 0; k < 128; ++k) s += pc[k];
            sqk[132] = s * S2;
        }
        __syncthreads();
    }

    // ---- positional score (+c0), exp2-prescaled, masked ----
    {
        const float qp0 = sqk[128], qp1 = sqk[129], qp2 = sqk[130], qp3 = sqk[131];
        const float c0  = sqk[132];
        #pragma unroll
        for (int s = tid; s < SEQ; s += 256) {
            float4 p4 = ((const float4*)pos)[(size_t)b * SEQ + s];
            float sc = fmaf(qp0, p4.x, fmaf(qp1, p4.y, fmaf(qp2, p4.z, fmaf(qp3, p4.w, c0))));
            if (mask[(size_t)b * SEQ + s] == 0) sc = -1e30f;
            spos[s + (s >> 7)] = sc;
        }
    }
    const float4 qk4 = *(const float4*)&sqk[4 * c];
    __syncthreads();

    const int sp0 = w * 129 + h;      // padded spos index of row (128w + h)

    float m = -INFINITY, den = 0.f;
    float ax = 0.f, ay = 0.f, az = 0.f, aw = 0.f;

#define PROC(V, J)                                                          \
    {                                                                       \
        float r = (V).x * qk4.x;                                            \
        r = fmaf((V).y, qk4.y, r);                                          \
        r = fmaf((V).z, qk4.z, r);                                          \
        r = fmaf((V).w, qk4.w, r);                                          \
        r = dpp_add<0x121>(r);                                              \
        r = dpp_add<0x122>(r);                                              \
        r = dpp_add<0x124>(r);                                              \
        r = dpp_add<0x128>(r);                                              \
        r += __shfl_xor(r, 16);                                             \
        float sc = r + spos[sp0 + 2 * (J)];                                 \
        float dd = sc - m;                                                  \
        if (__builtin_expect(dd > 8.0f, 0)) {                               \
            float f = __builtin_amdgcn_exp2f(-dd);                          \
            den = fmaf(den, f, 1.0f);                                       \
            ax = fmaf(ax, f, (V).x); ay = fmaf(ay, f, (V).y);               \
            az = fmaf(az, f, (V).z); aw = fmaf(aw, f, (V).w);               \
            m = sc;                                                         \
        } else {                                                            \
            float p = __builtin_amdgcn_exp2f(dd);                           \
            den += p;                                                       \
            ax = fmaf(p, (V).x, ax); ay = fmaf(p, (V).y, ay);               \
            az = fmaf(p, (V).z, az); aw = fmaf(p, (V).w, aw);               \
        }                                                                   \
    }

    // ---- 6-deep rotating pipeline; guards truncate 66 slots to 64 ----
#define STEP(V, J)                                                          \
    if ((J) < 64) {                                                         \
        PROC(V, J);                                                         \
        if ((J) + 6 < 64) V = xw[(((J) + 6) * 64) + l];                     \
    }

    #pragma unroll
    for (int ch = 0; ch < 11; ++ch) {
        const int base = 6 * ch;
        STEP(v0, base + 0);
        STEP(v1, base + 1);
        STEP(v2, base + 2);
        STEP(v3, base + 3);
        STEP(v4, base + 4);
        STEP(v5, base + 5);
    }
#undef STEP
#undef PROC

    // ---- merge the 8 states ----
    if (c == 0) { sm[st] = m; sl[st] = den; }
    __syncthreads();
    float gm = -INFINITY;
    #pragma unroll
    for (int k = 0; k < 8; ++k) gm = fmaxf(gm, sm[k]);
    float f = __builtin_amdgcn_exp2f(m - gm);
    sacc[st][4 * c + 0] = ax * f;
    sacc[st][4 * c + 1] = ay * f;
    sacc[st][4 * c + 2] = az * f;
    sacc[st][4 * c + 3] = aw * f;
    float gl = 0.f;
    #pragma unroll
    for (int k = 0; k < 8; ++k) gl += sl[k] * __builtin_amdgcn_exp2f(sm[k] - gm);
    __syncthreads();

    if (tid < DIM) {
        float s0 = 0.f;
        #pragma unroll
        for (int k = 0; k < 8; ++k) s0 += sacc[k][tid];
        t[tid] = s0;
    }
    __syncthreads();

    // ---- epilogue: pooled[b,k] = bv[k] + (Wv[k,:] . t) / gl ----
    if (tid < DIM) {
        const float4* wv4 = (const float4*)(Wv + tid * DIM);
        const float4* t4  = (const float4*)t;
        float sum = 0.f;
        #pragma unroll
        for (int j = 0; j < 32; ++j) {
            float4 wv = wv4[j];
            float4 tv = t4[j];
            sum += wv.x * tv.x + wv.y * tv.y + wv.z * tv.z + wv.w * tv.w;
        }
        out[(size_t)b * DIM + tid] = bv[tid] + sum / gl;
    }
}

extern "C" void kernel_launch(void* const* d_in, const int* in_sizes, int n_in,
                              void* d_out, int out_size, void* d_ws, size_t ws_size,
                              hipStream_t stream) {
    const float* x     = (const float*)d_in[0];
    const float* pos   = (const float*)d_in[1];
    const int*   mask  = (const int*)d_in[2];     // bool -> int32 per harness convention
    const float* query = (const float*)d_in[3];
    const float* Wk    = (const float*)d_in[4];
    const float* bk    = (const float*)d_in[5];
    const float* Wv    = (const float*)d_in[6];
    const float* bv    = (const float*)d_in[7];
    const float* Wp    = (const float*)d_in[8];
    const float* bp    = (const float*)d_in[9];
    float* out = (float*)d_out;

    ap_fused<<<BATCH, 256, 0, stream>>>(x, pos, mask, query, Wk, bk, Wv, bv, Wp, bp, out);
}

// Round 12
// 117.567 us; speedup vs baseline: 1.2384x; 1.2384x over previous
//
#include <hip/hip_runtime.h>
#include <math.h>

#define BATCH 2048
#define SEQ 512
#define DIM 128

// DPP rotate-within-16 add: after ror 1,2,4,8 every lane holds its 16-group sum.
template<int CTRL>
__device__ __forceinline__ float dpp_add(float x) {
    int y = __builtin_amdgcn_update_dpp(0, __float_as_int(x), CTRL, 0xf, 0xf, true);
    return x + __int_as_float(y);
}

// ws layout: [0..127] qk (SCALE*log2e), [128..131] qp, [132] c0 — exp2-prescaled
__global__ __launch_bounds__(256) void ap_prep(
    const float* __restrict__ query,
    const float* __restrict__ Wk, const float* __restrict__ bk,
    const float* __restrict__ Wp, const float* __restrict__ bp,
    float* __restrict__ ws)
{
    __shared__ float part[128];
    __shared__ float pq[128][4];
    __shared__ float pc[128];
    const float S2 = 0.08838834764831845f * 1.4426950408889634f;  // 128^-0.5 * log2(e)
    const int t = threadIdx.x;
    const int d = t & 127, hk = t >> 7;   // 2 threads per output d, k-split
    float acc = 0.f;
    const int k0 = hk * 64;
    #pragma unroll 16
    for (int k = 0; k < 64; ++k) acc += query[k0 + k] * Wk[(k0 + k) * 128 + d];
    if (hk) part[d] = acc;
    if (t < 128) {
        float q = query[t];
        float4 wp = ((const float4*)Wp)[t];
        pq[t][0] = q * wp.x; pq[t][1] = q * wp.y;
        pq[t][2] = q * wp.z; pq[t][3] = q * wp.w;
        pc[t] = q * (bk[t] + bp[t]);
    }
    __syncthreads();
    if (!hk) {
        ws[d] = (acc + part[d]) * S2;
    } else if (d < 4) {
        float s = 0.f;
        #pragma unroll
        for (int k = 0; k < 128; ++k) s += pq[k][d];
        ws[128 + d] = s * S2;
    } else if (d == 4) {
        float s = 0.f;
        #pragma unroll
        for (int k = 0; k < 128; ++k) s += pc[k];
        ws[132] = s * S2;
    }
}

__global__ __launch_bounds__(256, 8) void ap_main(
    const float* __restrict__ x, const float* __restrict__ pos,
    const int* __restrict__ mask,
    const float* __restrict__ Wv, const float* __restrict__ bv,
    const float* __restrict__ ws, float* __restrict__ out)
{
    __shared__ float spos[520];                    // padded: idx = s + (s>>7)
    __shared__ float sacc[8][DIM];
    __shared__ float sm[8], sl[8];
    __shared__ alignas(16) float t[DIM];

    const int b   = blockIdx.x;
    const int tid = threadIdx.x;
    const int l   = tid & 63;
    const int w   = tid >> 6;         // wave 0..3, owns rows [128w, 128w+128)
    const int h   = (tid >> 5) & 1;   // half: even(0)/odd(1) rows of the wave
    const int c   = tid & 31;         // column group (4 floats)
    const int st  = tid >> 5;         // merge state 0..7

    // ---- issue first 8 x-loads immediately (hide spos phase under them) ----
    const float4* xw = (const float4*)(x + (size_t)b * SEQ * DIM) + w * 4096;
    float4 v0 = xw[0 * 64 + l];
    float4 v1 = xw[1 * 64 + l];
    float4 v2 = xw[2 * 64 + l];
    float4 v3 = xw[3 * 64 + l];
    float4 v4 = xw[4 * 64 + l];
    float4 v5 = xw[5 * 64 + l];
    float4 v6 = xw[6 * 64 + l];
    float4 v7 = xw[7 * 64 + l];

    const float4 qk4 = ((const float4*)ws)[c];
    const float qp0 = ws[128], qp1 = ws[129], qp2 = ws[130], qp3 = ws[131];
    const float c0  = ws[132];

    // positional score (+c0), exp2-prescaled, masked; bank-conflict-padded
    #pragma unroll
    for (int s = tid; s < SEQ; s += 256) {
        float4 p4 = ((const float4*)pos)[(size_t)b * SEQ + s];
        float sc = fmaf(qp0, p4.x, fmaf(qp1, p4.y, fmaf(qp2, p4.z, fmaf(qp3, p4.w, c0))));
        if (mask[(size_t)b * SEQ + s] == 0) sc = -1e30f;
        spos[s + (s >> 7)] = sc;
    }
    __syncthreads();

    const int sp0 = w * 129 + h;      // padded spos index of row (128w + h)

    float m = -INFINITY, den = 0.f;
    float ax = 0.f, ay = 0.f, az = 0.f, aw = 0.f;

#define PROC(V, J)                                                          \
    {                                                                       \
        float r = (V).x * qk4.x;                                            \
        r = fmaf((V).y, qk4.y, r);                                          \
        r = fmaf((V).z, qk4.z, r);                                          \
        r = fmaf((V).w, qk4.w, r);                                          \
        r = dpp_add<0x121>(r);                                              \
        r = dpp_add<0x122>(r);                                              \
        r = dpp_add<0x124>(r);                                              \
        r = dpp_add<0x128>(r);                                              \
        r += __shfl_xor(r, 16);                                             \
        float sc = r + spos[sp0 + 2 * (J)];                                 \
        float dd = sc - m;                                                  \
        if (__builtin_expect(dd > 8.0f, 0)) {                               \
            float f = __builtin_amdgcn_exp2f(-dd);                          \
            den = fmaf(den, f, 1.0f);                                       \
            ax = fmaf(ax, f, (V).x); ay = fmaf(ay, f, (V).y);               \
            az = fmaf(az, f, (V).z); aw = fmaf(aw, f, (V).w);               \
            m = sc;                                                         \
        } else {                                                            \
            float p = __builtin_amdgcn_exp2f(dd);                           \
            den += p;                                                       \
            ax = fmaf(p, (V).x, ax); ay = fmaf(p, (V).y, ay);               \
            az = fmaf(p, (V).z, az); aw = fmaf(p, (V).w, aw);               \
        }                                                                   \
    }

    // ---- 8-deep rotating pipeline; exactly 8 chunks x 8 = 64 iterations ----
#define STEP(V, J)                                                          \
    {                                                                       \
        PROC(V, J);                                                         \
        if ((J) + 8 < 64) V = xw[(((J) + 8) * 64) + l];                     \
    }

    #pragma unroll
    for (int ch = 0; ch < 8; ++ch) {
        const int base = 8 * ch;
        STEP(v0, base + 0);
        STEP(v1, base + 1);
        STEP(v2, base + 2);
        STEP(v3, base + 3);
        STEP(v4, base + 4);
        STEP(v5, base + 5);
        STEP(v6, base + 6);
        STEP(v7, base + 7);
    }
#undef STEP
#undef PROC

    // ---- merge the 8 states ----
    if (c == 0) { sm[st] = m; sl[st] = den; }
    __syncthreads();
    float gm = -INFINITY;
    #pragma unroll
    for (int k = 0; k < 8; ++k) gm = fmaxf(gm, sm[k]);
    float f = __builtin_amdgcn_exp2f(m - gm);
    sacc[st][4 * c + 0] = ax * f;
    sacc[st][4 * c + 1] = ay * f;
    sacc[st][4 * c + 2] = az * f;
    sacc[st][4 * c + 3] = aw * f;
    float gl = 0.f;
    #pragma unroll
    for (int k = 0; k < 8; ++k) gl += sl[k] * __builtin_amdgcn_exp2f(sm[k] - gm);
    __syncthreads();

    if (tid < DIM) {
        float s0 = 0.f;
        #pragma unroll
        for (int k = 0; k < 8; ++k) s0 += sacc[k][tid];
        t[tid] = s0;
    }
    __syncthreads();

    // ---- epilogue: pooled[b,k] = bv[k] + (Wv[k,:] . t) / gl ----
    if (tid < DIM) {
        const float4* wv4 = (const float4*)(Wv + tid * DIM);
        const float4* t4  = (const float4*)t;
        float sum = 0.f;
        #pragma unroll
        for (int j = 0; j < 32; ++j) {
            float4 wv = wv4[j];
            float4 tv = t4[j];
            sum += wv.x * tv.x + wv.y * tv.y + wv.z * tv.z + wv.w * tv.w;
        }
        out[(size_t)b * DIM + tid] = bv[tid] + sum / gl;
    }
}

extern "C" void kernel_launch(void* const* d_in, const int* in_sizes, int n_in,
                              void* d_out, int out_size, void* d_ws, size_t ws_size,
                              hipStream_t stream) {
    const float* x     = (const float*)d_in[0];
    const float* pos   = (const float*)d_in[1];
    const int*   mask  = (const int*)d_in[2];     // bool -> int32 per harness convention
    const float* query = (const float*)d_in[3];
    const float* Wk    = (const float*)d_in[4];
    const float* bk    = (const float*)d_in[5];
    const float* Wv    = (const float*)d_in[6];
    const float* bv    = (const float*)d_in[7];
    const float* Wp    = (const float*)d_in[8];
    const float* bp    = (const float*)d_in[9];
    float* out = (float*)d_out;
    float* ws  = (float*)d_ws;

    ap_prep<<<1, 256, 0, stream>>>(query, Wk, bk, Wp, bp, ws);
    ap_main<<<BATCH, 256, 0, stream>>>(x, pos, mask, Wv, bv, ws, out);
}

// Round 13
// 106.349 us; speedup vs baseline: 1.3691x; 1.1055x over previous
//
#include <hip/hip_runtime.h>
#include <math.h>

#define BATCH 2048
#define SEQ 512
#define DIM 128

typedef float fx4 __attribute__((ext_vector_type(4)));  // native vec: nontemporal OK

// DPP rotate-within-16 add: after ror 1,2,4,8 every lane holds its 16-group sum.
template<int CTRL>
__device__ __forceinline__ float dpp_add(float x) {
    int y = __builtin_amdgcn_update_dpp(0, __float_as_int(x), CTRL, 0xf, 0xf, true);
    return x + __int_as_float(y);
}

// ws layout: [0..127] qk (SCALE*log2e), [128..131] qp, [132] c0 — exp2-prescaled
__global__ __launch_bounds__(256) void ap_prep(
    const float* __restrict__ query,
    const float* __restrict__ Wk, const float* __restrict__ bk,
    const float* __restrict__ Wp, const float* __restrict__ bp,
    float* __restrict__ ws)
{
    __shared__ float part[128];
    __shared__ float pq[128][4];
    __shared__ float pc[128];
    const float S2 = 0.08838834764831845f * 1.4426950408889634f;  // 128^-0.5 * log2(e)
    const int t = threadIdx.x;
    const int d = t & 127, hk = t >> 7;   // 2 threads per output d, k-split
    float acc = 0.f;
    const int k0 = hk * 64;
    #pragma unroll 16
    for (int k = 0; k < 64; ++k) acc += query[k0 + k] * Wk[(k0 + k) * 128 + d];
    if (hk) part[d] = acc;
    if (t < 128) {
        float q = query[t];
        float4 wp = ((const float4*)Wp)[t];
        pq[t][0] = q * wp.x; pq[t][1] = q * wp.y;
        pq[t][2] = q * wp.z; pq[t][3] = q * wp.w;
        pc[t] = q * (bk[t] + bp[t]);
    }
    __syncthreads();
    if (!hk) {
        ws[d] = (acc + part[d]) * S2;
    } else if (d < 4) {
        float s = 0.f;
        #pragma unroll
        for (int k = 0; k < 128; ++k) s += pq[k][d];
        ws[128 + d] = s * S2;
    } else if (d == 4) {
        float s = 0.f;
        #pragma unroll
        for (int k = 0; k < 128; ++k) s += pc[k];
        ws[132] = s * S2;
    }
}

__global__ __launch_bounds__(256, 8) void ap_main(
    const float* __restrict__ x, const float* __restrict__ pos,
    const int* __restrict__ mask,
    const float* __restrict__ Wv, const float* __restrict__ bv,
    const float* __restrict__ ws, float* __restrict__ out)
{
    __shared__ float spos[520];                    // padded: idx = s + (s>>7)
    __shared__ float sacc[8][DIM];
    __shared__ float sm[8], sl[8];
    __shared__ alignas(16) float t[DIM];

    const int b   = blockIdx.x;
    const int tid = threadIdx.x;
    const int l   = tid & 63;
    const int w   = tid >> 6;         // wave 0..3, owns rows [128w, 128w+128)
    const int h   = (tid >> 5) & 1;   // half: even(0)/odd(1) rows of the wave
    const int c   = tid & 31;         // column group (4 floats)
    const int st  = tid >> 5;         // merge state 0..7

    // ---- issue first 8 x-loads immediately (hide spos phase under them) ----
    // nontemporal: x is a read-once 512MB stream; don't allocate it in cache.
    const fx4* xw = (const fx4*)(x + (size_t)b * SEQ * DIM) + w * 4096;
    fx4 v0 = __builtin_nontemporal_load(xw + 0 * 64 + l);
    fx4 v1 = __builtin_nontemporal_load(xw + 1 * 64 + l);
    fx4 v2 = __builtin_nontemporal_load(xw + 2 * 64 + l);
    fx4 v3 = __builtin_nontemporal_load(xw + 3 * 64 + l);
    fx4 v4 = __builtin_nontemporal_load(xw + 4 * 64 + l);
    fx4 v5 = __builtin_nontemporal_load(xw + 5 * 64 + l);
    fx4 v6 = __builtin_nontemporal_load(xw + 6 * 64 + l);
    fx4 v7 = __builtin_nontemporal_load(xw + 7 * 64 + l);

    const float4 qk4 = ((const float4*)ws)[c];
    const float qp0 = ws[128], qp1 = ws[129], qp2 = ws[130], qp3 = ws[131];
    const float c0  = ws[132];

    // positional score (+c0), exp2-prescaled, masked; bank-conflict-padded
    #pragma unroll
    for (int s = tid; s < SEQ; s += 256) {
        float4 p4 = ((const float4*)pos)[(size_t)b * SEQ + s];
        float sc = fmaf(qp0, p4.x, fmaf(qp1, p4.y, fmaf(qp2, p4.z, fmaf(qp3, p4.w, c0))));
        if (mask[(size_t)b * SEQ + s] == 0) sc = -1e30f;
        spos[s + (s >> 7)] = sc;
    }
    __syncthreads();

    const int sp0 = w * 129 + h;      // padded spos index of row (128w + h)

    float m = -INFINITY, den = 0.f;
    float ax = 0.f, ay = 0.f, az = 0.f, aw = 0.f;

#define PROC(V, J)                                                          \
    {                                                                       \
        float r = (V).x * qk4.x;                                            \
        r = fmaf((V).y, qk4.y, r);                                          \
        r = fmaf((V).z, qk4.z, r);                                          \
        r = fmaf((V).w, qk4.w, r);                                          \
        r = dpp_add<0x121>(r);                                              \
        r = dpp_add<0x122>(r);                                              \
        r = dpp_add<0x124>(r);                                              \
        r = dpp_add<0x128>(r);                                              \
        r += __shfl_xor(r, 16);                                             \
        float sc = r + spos[sp0 + 2 * (J)];                                 \
        float dd = sc - m;                                                  \
        if (__builtin_expect(dd > 8.0f, 0)) {                               \
            float f = __builtin_amdgcn_exp2f(-dd);                          \
            den = fmaf(den, f, 1.0f);                                       \
            ax = fmaf(ax, f, (V).x); ay = fmaf(ay, f, (V).y);               \
            az = fmaf(az, f, (V).z); aw = fmaf(aw, f, (V).w);               \
            m = sc;                                                         \
        } else {                                                            \
            float p = __builtin_amdgcn_exp2f(dd);                           \
            den += p;                                                       \
            ax = fmaf(p, (V).x, ax); ay = fmaf(p, (V).y, ay);               \
            az = fmaf(p, (V).z, az); aw = fmaf(p, (V).w, aw);               \
        }                                                                   \
    }

    // ---- 8-deep rotating pipeline; exactly 8 chunks x 8 = 64 iterations ----
#define STEP(V, J)                                                          \
    {                                                                       \
        PROC(V, J);                                                         \
        if ((J) + 8 < 64) V = __builtin_nontemporal_load(xw + (((J) + 8) * 64) + l); \
    }

    #pragma unroll
    for (int ch = 0; ch < 8; ++ch) {
        const int base = 8 * ch;
        STEP(v0, base + 0);
        STEP(v1, base + 1);
        STEP(v2, base + 2);
        STEP(v3, base + 3);
        STEP(v4, base + 4);
        STEP(v5, base + 5);
        STEP(v6, base + 6);
        STEP(v7, base + 7);
    }
#undef STEP
#undef PROC

    // ---- merge the 8 states ----
    if (c == 0) { sm[st] = m; sl[st] = den; }
    __syncthreads();
    float gm = -INFINITY;
    #pragma unroll
    for (int k = 0; k < 8; ++k) gm = fmaxf(gm, sm[k]);
    float f = __builtin_amdgcn_exp2f(m - gm);
    sacc[st][4 * c + 0] = ax * f;
    sacc[st][4 * c + 1] = ay * f;
    sacc[st][4 * c + 2] = az * f;
    sacc[st][4 * c + 3] = aw * f;
    float gl = 0.f;
    #pragma unroll
    for (int k = 0; k < 8; ++k) gl += sl[k] * __builtin_amdgcn_exp2f(sm[k] - gm);
    __syncthreads();

    if (tid < DIM) {
        float s0 = 0.f;
        #pragma unroll
        for (int k = 0; k < 8; ++k) s0 += sacc[k][tid];
        t[tid] = s0;
    }
    __syncthreads();

    // ---- epilogue: pooled[b,k] = bv[k] + (Wv[k,:] . t) / gl ----
    if (tid < DIM) {
        const float4* wv4 = (const float4*)(Wv + tid * DIM);
        const float4* t4  = (const float4*)t;
        float sum = 0.f;
        #pragma unroll
        for (int j = 0; j < 32; ++j) {
            float4 wv = wv4[j];
            float4 tv = t4[j];
            sum += wv.x * tv.x + wv.y * tv.y + wv.z * tv.z + wv.w * tv.w;
        }
        out[(size_t)b * DIM + tid] = bv[tid] + sum / gl;
    }
}

extern "C" void kernel_launch(void* const* d_in, const int* in_sizes, int n_in,
                              void* d_out, int out_size, void* d_ws, size_t ws_size,
                              hipStream_t stream) {
    const float* x     = (const float*)d_in[0];
    const float* pos   = (const float*)d_in[1];
    const int*   mask  = (const int*)d_in[2];     // bool -> int32 per harness convention
    const float* query = (const float*)d_in[3];
    const float* Wk    = (const float*)d_in[4];
    const float* bk    = (const float*)d_in[5];
    const float* Wv    = (const float*)d_in[6];
    const float* bv    = (const float*)d_in[7];
    const float* Wp    = (const float*)d_in[8];
    const float* bp    = (const float*)d_in[9];
    float* out = (float*)d_out;
    float* ws  = (float*)d_ws;

    ap_prep<<<1, 256, 0, stream>>>(query, Wk, bk, Wp, bp, ws);
    ap_main<<<BATCH, 256, 0, stream>>>(x, pos, mask, Wv, bv, ws, out);
}

// Round 14
// 100.666 us; speedup vs baseline: 1.4464x; 1.0565x over previous
//
#include <hip/hip_runtime.h>
#include <math.h>

#define BATCH 2048
#define SEQ 512
#define DIM 128

typedef float fx4 __attribute__((ext_vector_type(4)));  // native vec: nontemporal OK

// DPP rotate-within-16 add: after ror 1,2,4,8 every lane holds its 16-group sum.
template<int CTRL>
__device__ __forceinline__ float dpp_add(float x) {
    int y = __builtin_amdgcn_update_dpp(0, __float_as_int(x), CTRL, 0xf, 0xf, true);
    return x + __int_as_float(y);
}

// ws layout: [0..127] qk (SCALE*log2e), [128..131] qp, [132] c0 — exp2-prescaled
__global__ __launch_bounds__(256) void ap_prep(
    const float* __restrict__ query,
    const float* __restrict__ Wk, const float* __restrict__ bk,
    const float* __restrict__ Wp, const float* __restrict__ bp,
    float* __restrict__ ws)
{
    __shared__ float part[128];
    __shared__ float pq[128][4];
    __shared__ float pc[128];
    const float S2 = 0.08838834764831845f * 1.4426950408889634f;  // 128^-0.5 * log2(e)
    const int t = threadIdx.x;
    const int d = t & 127, hk = t >> 7;   // 2 threads per output d, k-split
    float acc = 0.f;
    const int k0 = hk * 64;
    #pragma unroll 16
    for (int k = 0; k < 64; ++k) acc += query[k0 + k] * Wk[(k0 + k) * 128 + d];
    if (hk) part[d] = acc;
    if (t < 128) {
        float q = query[t];
        float4 wp = ((const float4*)Wp)[t];
        pq[t][0] = q * wp.x; pq[t][1] = q * wp.y;
        pq[t][2] = q * wp.z; pq[t][3] = q * wp.w;
        pc[t] = q * (bk[t] + bp[t]);
    }
    __syncthreads();
    if (!hk) {
        ws[d] = (acc + part[d]) * S2;
    } else if (d < 4) {
        float s = 0.f;
        #pragma unroll
        for (int k = 0; k < 128; ++k) s += pq[k][d];
        ws[128 + d] = s * S2;
    } else if (d == 4) {
        float s = 0.f;
        #pragma unroll
        for (int k = 0; k < 128; ++k) s += pc[k];
        ws[132] = s * S2;
    }
}

__global__ __launch_bounds__(256, 8) void ap_main(
    const float* __restrict__ x, const float* __restrict__ pos,
    const int* __restrict__ mask,
    const float* __restrict__ Wv, const float* __restrict__ bv,
    const float* __restrict__ ws, float* __restrict__ out)
{
    __shared__ float spos[520];                    // padded: idx = s + (s>>7)
    __shared__ float sacc[8][DIM];
    __shared__ float sm[8], sl[8];
    __shared__ alignas(16) float t[DIM];

    const int b   = blockIdx.x;
    const int tid = threadIdx.x;
    const int l   = tid & 63;
    const int w   = tid >> 6;         // wave 0..3, owns rows [128w, 128w+128)
    const int h   = (tid >> 5) & 1;   // half: even(0)/odd(1) rows of the wave
    const int c   = tid & 31;         // column group (4 floats)
    const int st  = tid >> 5;         // merge state 0..7

    // ---- issue first 8 x-loads immediately (hide spos phase under them) ----
    // nontemporal: read-once streams don't allocate in cache.
    const fx4* xw = (const fx4*)(x + (size_t)b * SEQ * DIM) + w * 4096;
    fx4 v0 = __builtin_nontemporal_load(xw + 0 * 64 + l);
    fx4 v1 = __builtin_nontemporal_load(xw + 1 * 64 + l);
    fx4 v2 = __builtin_nontemporal_load(xw + 2 * 64 + l);
    fx4 v3 = __builtin_nontemporal_load(xw + 3 * 64 + l);
    fx4 v4 = __builtin_nontemporal_load(xw + 4 * 64 + l);
    fx4 v5 = __builtin_nontemporal_load(xw + 5 * 64 + l);
    fx4 v6 = __builtin_nontemporal_load(xw + 6 * 64 + l);
    fx4 v7 = __builtin_nontemporal_load(xw + 7 * 64 + l);

    const float4 qk4 = ((const float4*)ws)[c];
    const float qp0 = ws[128], qp1 = ws[129], qp2 = ws[130], qp3 = ws[131];
    const float c0  = ws[132];

    // positional score (+c0), exp2-prescaled, masked; bank-conflict-padded
    #pragma unroll
    for (int s = tid; s < SEQ; s += 256) {
        fx4 p4 = __builtin_nontemporal_load((const fx4*)pos + (size_t)b * SEQ + s);
        float sc = fmaf(qp0, p4.x, fmaf(qp1, p4.y, fmaf(qp2, p4.z, fmaf(qp3, p4.w, c0))));
        if (__builtin_nontemporal_load(mask + (size_t)b * SEQ + s) == 0) sc = -1e30f;
        spos[s + (s >> 7)] = sc;
    }
    __syncthreads();

    const int sp0 = w * 129 + h;      // padded spos index of row (128w + h)

    float m = -INFINITY, den = 0.f;
    float ax = 0.f, ay = 0.f, az = 0.f, aw = 0.f;

#define PROC(V, J)                                                          \
    {                                                                       \
        float r = (V).x * qk4.x;                                            \
        r = fmaf((V).y, qk4.y, r);                                          \
        r = fmaf((V).z, qk4.z, r);                                          \
        r = fmaf((V).w, qk4.w, r);                                          \
        r = dpp_add<0x121>(r);                                              \
        r = dpp_add<0x122>(r);                                              \
        r = dpp_add<0x124>(r);                                              \
        r = dpp_add<0x128>(r);                                              \
        r += __shfl_xor(r, 16);                                             \
        float sc = r + spos[sp0 + 2 * (J)];                                 \
        float dd = sc - m;                                                  \
        if (__builtin_expect(dd > 8.0f, 0)) {                               \
            float f = __builtin_amdgcn_exp2f(-dd);                          \
            den = fmaf(den, f, 1.0f);                                       \
            ax = fmaf(ax, f, (V).x); ay = fmaf(ay, f, (V).y);               \
            az = fmaf(az, f, (V).z); aw = fmaf(aw, f, (V).w);               \
            m = sc;                                                         \
        } else {                                                            \
            float p = __builtin_amdgcn_exp2f(dd);                           \
            den += p;                                                       \
            ax = fmaf(p, (V).x, ax); ay = fmaf(p, (V).y, ay);               \
            az = fmaf(p, (V).z, az); aw = fmaf(p, (V).w, aw);               \
        }                                                                   \
    }

    // ---- 8-deep rotating pipeline; exactly 8 chunks x 8 = 64 iterations ----
#define STEP(V, J)                                                          \
    {                                                                       \
        PROC(V, J);                                                         \
        if ((J) + 8 < 64) V = __builtin_nontemporal_load(xw + (((J) + 8) * 64) + l); \
    }

    #pragma unroll
    for (int ch = 0; ch < 8; ++ch) {
        const int base = 8 * ch;
        STEP(v0, base + 0);
        STEP(v1, base + 1);
        STEP(v2, base + 2);
        STEP(v3, base + 3);
        STEP(v4, base + 4);
        STEP(v5, base + 5);
        STEP(v6, base + 6);
        STEP(v7, base + 7);
    }
#undef STEP
#undef PROC

    // ---- merge the 8 states ----
    if (c == 0) { sm[st] = m; sl[st] = den; }
    __syncthreads();
    float gm = -INFINITY;
    #pragma unroll
    for (int k = 0; k < 8; ++k) gm = fmaxf(gm, sm[k]);
    float f = __builtin_amdgcn_exp2f(m - gm);
    sacc[st][4 * c + 0] = ax * f;
    sacc[st][4 * c + 1] = ay * f;
    sacc[st][4 * c + 2] = az * f;
    sacc[st][4 * c + 3] = aw * f;
    float gl = 0.f;
    #pragma unroll
    for (int k = 0; k < 8; ++k) gl += sl[k] * __builtin_amdgcn_exp2f(sm[k] - gm);
    __syncthreads();

    if (tid < DIM) {
        float s0 = 0.f;
        #pragma unroll
        for (int k = 0; k < 8; ++k) s0 += sacc[k][tid];
        t[tid] = s0;
    }
    __syncthreads();

    // ---- epilogue: pooled[b,k] = bv[k] + (Wv[k,:] . t) / gl ----
    // all 256 threads: pair (tid, tid+... ) — thread handles output (tid&127),
    // half (tid>>7): 16 float4 FMAs each, partner-combine via LDS-free shfl.
    {
        const int k  = tid & 127;          // output index
        const int hh = tid >> 7;           // which half of the dot
        const float4* wv4 = (const float4*)(Wv + k * DIM) + hh * 16;
        const float4* t4  = (const float4*)t + hh * 16;
        float sum = 0.f;
        #pragma unroll
        for (int j = 0; j < 16; ++j) {
            float4 wv = wv4[j];
            float4 tv = t4[j];
            sum += wv.x * tv.x + wv.y * tv.y + wv.z * tv.z + wv.w * tv.w;
        }
        // combine the two halves: threads tid and tid^128 live in different
        // waves, so use LDS (reuse sacc row 0..1 as scratch).
        ((float*)sacc)[tid] = sum;
        __syncthreads();
        if (tid < DIM) {
            float s2 = ((float*)sacc)[tid] + ((float*)sacc)[tid + 128];
            out[(size_t)b * DIM + tid] = bv[tid] + s2 / gl;
        }
    }
}

extern "C" void kernel_launch(void* const* d_in, const int* in_sizes, int n_in,
                              void* d_out, int out_size, void* d_ws, size_t ws_size,
                              hipStream_t stream) {
    const float* x     = (const float*)d_in[0];
    const float* pos   = (const float*)d_in[1];
    const int*   mask  = (const int*)d_in[2];     // bool -> int32 per harness convention
    const float* query = (const float*)d_in[3];
    const float* Wk    = (const float*)d_in[4];
    const float* bk    = (const float*)d_in[5];
    const float* Wv    = (const float*)d_in[6];
    const float* bv    = (const float*)d_in[7];
    const float* Wp    = (const float*)d_in[8];
    const float* bp    = (const float*)d_in[9];
    float* out = (float*)d_out;
    float* ws  = (float*)d_ws;

    ap_prep<<<1, 256, 0, stream>>>(query, Wk, bk, Wp, bp, ws);
    ap_main<<<BATCH, 256, 0, stream>>>(x, pos, mask, Wv, bv, ws, out);
}